// Round 4
// baseline (1524.508 us; speedup 1.0000x reference)
//
#include <hip/hip_runtime.h>

// GroupQLinear: dequant(int8 group-quant) -> GEMM -> bias -> group requant.
// e = floor(log2(absmax/gmax)) is DISCRETE -> y must be ~1e-7-accurate.
//
// All-integer scheme: X = q*2^(15-e) is an exact 22-bit int at the common
// per-token scale delta*2^-15 (3 balanced i8 digits). W ~= W29*2^(E-29),
// W29 = rintf(w*2^(29-E)) (4 balanced i8 digits, residual rel ~2^-30).
// 11 digit-pair products (i+j<=4) via mfma_i32_32x32x32_i8, exact i32
// accumulation over ALL of K (max 3*128*128*4096 < 2^31), 5 accumulators
// grouped by digit-sum. One f64 Horner combine in the epilogue.

typedef __attribute__((ext_vector_type(4)))  int int32x4;
typedef __attribute__((ext_vector_type(16))) int int32x16;

// ---------------- prep kernels ----------------

__global__ __launch_bounds__(256) void wprep_rowmax(const float* __restrict__ W,
                                                    int* __restrict__ Eexp, int K) {
    const int o = blockIdx.x;
    const float* row = W + (size_t)o * K;
    float m = 0.f;
    for (int k = threadIdx.x; k < K; k += 256) m = fmaxf(m, fabsf(row[k]));
    __shared__ float red[256];
    red[threadIdx.x] = m;
    __syncthreads();
    for (int s = 128; s >= 1; s >>= 1) {
        if (threadIdx.x < s) red[threadIdx.x] = fmaxf(red[threadIdx.x], red[threadIdx.x + s]);
        __syncthreads();
    }
    if (threadIdx.x == 0) Eexp[o] = (red[0] > 0.f) ? ilogbf(red[0]) : 0;
}

// 4 balanced-digit planes of W29 = rintf(w * 2^(29-E)).  Plane j holds byte (3-j)
// (weight 2^(8*(3-j))), stored as [N][K] i8, k-contiguous.
__global__ __launch_bounds__(256) void wprep_slice(const float* __restrict__ W,
                                                   const int* __restrict__ Eexp,
                                                   signed char* __restrict__ wp,
                                                   size_t planeN, int K) {
    const int o = blockIdx.x;
    const int E = Eexp[o];
    const float s = ldexpf(1.0f, 29 - E);
    const float* row = W + (size_t)o * K;
    for (int k = threadIdx.x * 4; k < K; k += 1024) {
        float4 wv = *(const float4*)&row[k];
        const float v[4] = {wv.x, wv.y, wv.z, wv.w};
        unsigned C[4];
#pragma unroll
        for (int i = 0; i < 4; ++i) {
            int W29 = (int)rintf(v[i] * s);
            C[i] = ((unsigned)W29 + 0x80808080u) ^ 0x80808080u;
        }
#pragma unroll
        for (int b = 0; b < 4; ++b) {
            const unsigned sel = (unsigned)(((4 + b) << 8) | b);
            unsigned s01 = __builtin_amdgcn_perm(C[1], C[0], sel);
            unsigned s23 = __builtin_amdgcn_perm(C[3], C[2], sel);
            unsigned word = __builtin_amdgcn_perm(s23, s01, 0x05040100u);
            *(unsigned*)(wp + (size_t)(3 - b) * planeN + (size_t)o * K + k) = word;
        }
    }
}

__global__ __launch_bounds__(256) void xprep(const int* __restrict__ xq,
                                             signed char* __restrict__ q8, int K) {
    const int m = blockIdx.x;
    const int* row = xq + (size_t)m * K;
    signed char* out = q8 + (size_t)m * K;
    for (int k = threadIdx.x * 4; k < K; k += 1024) {
        int4 v = *(const int4*)&row[k];
        *(int*)&out[k] = (v.x & 0xFF) | ((v.y & 0xFF) << 8) | ((v.z & 0xFF) << 16) | (v.w << 24);
    }
}

// ---------------- all-int GEMM ----------------
// 256 thr = 4 waves; block tile 128m x 64o; BK=32 (one quant group).
// wave tile 32m x 64o = 2 subtiles of 32x32. D rows = o (A-op = W digits),
// D cols = m (B-op = X digits).
// LDS: X planes [2 kb][128 row][16B] with kb stride padded +16B; W planes
// [2 kb][64 row][16B] padded likewise.

#define XKB 2064
#define XPL (2 * XKB)
#define WKB 1040
#define WPL (2 * WKB)
#define XPOFF(i) ((i) * XPL)
#define WPOFF(j) (3 * XPL + (j) * WPL)
#define SMEM_SZ (3 * XPL + 4 * WPL)   // 20704

__global__ __launch_bounds__(256, 2) void gemm_int(
    const signed char* __restrict__ q8,   // [M][K] packed int8
    const int* __restrict__ xe,           // [M][K/32]
    const float* __restrict__ xdelta,     // [M]
    const signed char* __restrict__ wp,   // 4 planes [N][K] i8
    const int* __restrict__ Eexp,         // [N]
    const float* __restrict__ bias,       // [N]
    float* __restrict__ y,                // [M][N] f32
    int M, int N, int K)
{
    __shared__ alignas(16) char smem[SMEM_SZ];

    const int tid = threadIdx.x;
    const int m0 = blockIdx.y * 128;
    const int n0 = blockIdx.x * 64;
    const int Kg = K >> 5;
    const size_t planeN = (size_t)N * K;

    // staging ids
    const int arow = tid & 127, kh = tid >> 7;       // A: row 0..127, k-half 0/1
    const int orow = tid >> 2,  kq = (tid & 3) * 8;  // W: row 0..63, k-chunk 0/8/16/24
    // mfma ids
    const int w = tid >> 6, lane = tid & 63, lj = lane & 31, hi = lane >> 5;
    const int m_w = w * 32;

    int32x16 acc[2][5];
#pragma unroll
    for (int s = 0; s < 2; ++s)
#pragma unroll
        for (int g = 0; g < 5; ++g)
#pragma unroll
            for (int r = 0; r < 16; ++r) acc[s][g][r] = 0;

    const signed char* abase = q8 + (size_t)(m0 + arow) * K + kh * 16;
    const int*         ebase = xe + (size_t)(m0 + arow) * Kg;
    const signed char* wbase = wp + (size_t)(n0 + orow) * K + kq;

    // prefetch k-tile 0
    int4 pa = *(const int4*)(abase);
    int  pe = ebase[0];
    long pw0 = *(const long*)(wbase);
    long pw1 = *(const long*)(wbase + planeN);
    long pw2 = *(const long*)(wbase + 2 * planeN);
    long pw3 = *(const long*)(wbase + 3 * planeN);

    for (int kt = 0; kt < K; kt += 32) {
        __syncthreads();   // previous compute done; LDS free
        // ---- stage registers -> LDS ----
        {
            const int mul = 1 << (15 - pe);
            int pl0[4], pl1[4], pl2[4];
#pragma unroll
            for (int d = 0; d < 4; ++d) {
                const int dw = (d == 0) ? pa.x : (d == 1) ? pa.y : (d == 2) ? pa.z : pa.w;
                unsigned C[4];
#pragma unroll
                for (int b = 0; b < 4; ++b) {
                    const int q = (dw << (24 - 8 * b)) >> 24;  // sext byte b
                    const int X = q * mul;                     // exact, |X| <= 2^22
                    C[b] = ((unsigned)X + 0x00808080u) ^ 0x00808080u;
                }
                // plane i holds byte (2-i) of C (weight 2^(8*(2-i)))
                {
                    unsigned s01 = __builtin_amdgcn_perm(C[1], C[0], 0x0602u);
                    unsigned s23 = __builtin_amdgcn_perm(C[3], C[2], 0x0602u);
                    pl0[d] = (int)__builtin_amdgcn_perm(s23, s01, 0x05040100u);
                }
                {
                    unsigned s01 = __builtin_amdgcn_perm(C[1], C[0], 0x0501u);
                    unsigned s23 = __builtin_amdgcn_perm(C[3], C[2], 0x0501u);
                    pl1[d] = (int)__builtin_amdgcn_perm(s23, s01, 0x05040100u);
                }
                {
                    unsigned s01 = __builtin_amdgcn_perm(C[1], C[0], 0x0400u);
                    unsigned s23 = __builtin_amdgcn_perm(C[3], C[2], 0x0400u);
                    pl2[d] = (int)__builtin_amdgcn_perm(s23, s01, 0x05040100u);
                }
            }
            const int axo = kh * XKB + arow * 16;
            *(int4*)(smem + XPOFF(0) + axo) = make_int4(pl0[0], pl0[1], pl0[2], pl0[3]);
            *(int4*)(smem + XPOFF(1) + axo) = make_int4(pl1[0], pl1[1], pl1[2], pl1[3]);
            *(int4*)(smem + XPOFF(2) + axo) = make_int4(pl2[0], pl2[1], pl2[2], pl2[3]);

            const int wxo = (kq >> 4) * WKB + orow * 16 + (kq & 8);
            *(long*)(smem + WPOFF(0) + wxo) = pw0;
            *(long*)(smem + WPOFF(1) + wxo) = pw1;
            *(long*)(smem + WPOFF(2) + wxo) = pw2;
            *(long*)(smem + WPOFF(3) + wxo) = pw3;
        }
        // ---- prefetch next tile ----
        if (kt + 32 < K) {
            const int kn = kt + 32;
            pa  = *(const int4*)(abase + kn);
            pe  = ebase[kn >> 5];
            pw0 = *(const long*)(wbase + kn);
            pw1 = *(const long*)(wbase + kn + planeN);
            pw2 = *(const long*)(wbase + kn + 2 * planeN);
            pw3 = *(const long*)(wbase + kn + 3 * planeN);
        }
        __syncthreads();   // LDS ready
        // ---- compute: 11 digit-pair MFMAs per subtile ----
        {
            const int xro = hi * XKB + (m_w + lj) * 16;
            int32x4 xf0 = *(const int32x4*)(smem + XPOFF(0) + xro);
            int32x4 xf1 = *(const int32x4*)(smem + XPOFF(1) + xro);
            int32x4 xf2 = *(const int32x4*)(smem + XPOFF(2) + xro);
#pragma unroll
            for (int s = 0; s < 2; ++s) {
                const int wro = hi * WKB + (32 * s + lj) * 16;
                int32x4 wf;
                wf = *(const int32x4*)(smem + WPOFF(0) + wro);
                acc[s][0] = __builtin_amdgcn_mfma_i32_32x32x32_i8(wf, xf0, acc[s][0], 0, 0, 0);
                acc[s][1] = __builtin_amdgcn_mfma_i32_32x32x32_i8(wf, xf1, acc[s][1], 0, 0, 0);
                acc[s][2] = __builtin_amdgcn_mfma_i32_32x32x32_i8(wf, xf2, acc[s][2], 0, 0, 0);
                wf = *(const int32x4*)(smem + WPOFF(1) + wro);
                acc[s][1] = __builtin_amdgcn_mfma_i32_32x32x32_i8(wf, xf0, acc[s][1], 0, 0, 0);
                acc[s][2] = __builtin_amdgcn_mfma_i32_32x32x32_i8(wf, xf1, acc[s][2], 0, 0, 0);
                acc[s][3] = __builtin_amdgcn_mfma_i32_32x32x32_i8(wf, xf2, acc[s][3], 0, 0, 0);
                wf = *(const int32x4*)(smem + WPOFF(2) + wro);
                acc[s][2] = __builtin_amdgcn_mfma_i32_32x32x32_i8(wf, xf0, acc[s][2], 0, 0, 0);
                acc[s][3] = __builtin_amdgcn_mfma_i32_32x32x32_i8(wf, xf1, acc[s][3], 0, 0, 0);
                acc[s][4] = __builtin_amdgcn_mfma_i32_32x32x32_i8(wf, xf2, acc[s][4], 0, 0, 0);
                wf = *(const int32x4*)(smem + WPOFF(3) + wro);
                acc[s][3] = __builtin_amdgcn_mfma_i32_32x32x32_i8(wf, xf0, acc[s][3], 0, 0, 0);
                acc[s][4] = __builtin_amdgcn_mfma_i32_32x32x32_i8(wf, xf1, acc[s][4], 0, 0, 0);
            }
        }
    }

    // ---- epilogue: f64 Horner combine, scale, transpose via LDS, store ----
    __syncthreads();
    const double delta_d = (double)xdelta[m0 + m_w + lj];
    float* tw = (float*)(void*)smem + w * 1056;   // 32x33 f32 per wave
#pragma unroll
    for (int s = 0; s < 2; ++s) {
#pragma unroll
        for (int r = 0; r < 16; ++r) {
            const int ol = (r & 3) + 8 * (r >> 2) + 4 * hi;   // o_local in subtile
            const int o = n0 + 32 * s + ol;
            const double c8 = 1.0 / 256.0;
            double h = (double)acc[s][0][r]
                     + c8 * ((double)acc[s][1][r]
                     + c8 * ((double)acc[s][2][r]
                     + c8 * ((double)acc[s][3][r]
                     + c8 *  (double)acc[s][4][r])));
            double v = fma(ldexp(delta_d, Eexp[o] - 4), h, (double)bias[o]);
            tw[ol * 33 + lj] = (float)v;
        }
        __syncthreads();
#pragma unroll
        for (int it = 0; it < 16; ++it) {
            const int mr = 2 * it + hi;
            y[(size_t)(m0 + m_w + mr) * N + (n0 + 32 * s + lj)] = tw[lj * 33 + mr];
        }
        __syncthreads();
    }
}

// ---------------- fallback f64 GEMM (known-good, r2) ----------------

#define TM 128
#define TN 128
#define TK 16
#define LDT 132

__global__ __launch_bounds__(256, 2) void gemm_dq_kernel(
    const int* __restrict__ xq, const float* __restrict__ xdelta,
    const int* __restrict__ xe, const float* __restrict__ W,
    const float* __restrict__ bias, float* __restrict__ y,
    int M, int N, int K)
{
    __shared__ float As[TK][LDT];
    __shared__ float Bs[TK][LDT];
    const int tid = threadIdx.x;
    const int tx = tid & 15;
    const int ty = tid >> 4;
    const int m0 = blockIdx.y * TM;
    const int n0 = blockIdx.x * TN;
    const int srow = tid >> 1;
    const int scol = (tid & 1) * 8;
    const int Kg = K >> 5;
    const int*   aptr = xq + (size_t)(m0 + srow) * K + scol;
    const float* bptr = W  + (size_t)(n0 + srow) * K + scol;
    const float  adelta = xdelta[m0 + srow];
    const int*   aeptr  = xe + (size_t)(m0 + srow) * Kg;
    int4 pa0, pa1; float4 pb0, pb1; float pscale;
    pa0 = *(const int4*)(aptr);
    pa1 = *(const int4*)(aptr + 4);
    pb0 = *(const float4*)(bptr);
    pb1 = *(const float4*)(bptr + 4);
    pscale = adelta * exp2f(-(float)aeptr[scol >> 5]);
    double acc[8][8];
#pragma unroll
    for (int i = 0; i < 8; ++i)
#pragma unroll
        for (int j = 0; j < 8; ++j) acc[i][j] = 0.0;
    for (int kt = 0; kt < K; kt += TK) {
        {
            float* as = &As[scol][srow];
            as[0*LDT] = (float)pa0.x * pscale; as[1*LDT] = (float)pa0.y * pscale;
            as[2*LDT] = (float)pa0.z * pscale; as[3*LDT] = (float)pa0.w * pscale;
            as[4*LDT] = (float)pa1.x * pscale; as[5*LDT] = (float)pa1.y * pscale;
            as[6*LDT] = (float)pa1.z * pscale; as[7*LDT] = (float)pa1.w * pscale;
            float* bs = &Bs[scol][srow];
            bs[0*LDT] = pb0.x; bs[1*LDT] = pb0.y; bs[2*LDT] = pb0.z; bs[3*LDT] = pb0.w;
            bs[4*LDT] = pb1.x; bs[5*LDT] = pb1.y; bs[6*LDT] = pb1.z; bs[7*LDT] = pb1.w;
        }
        __syncthreads();
        if (kt + TK < K) {
            const int k1 = kt + TK;
            pa0 = *(const int4*)(aptr + k1);
            pa1 = *(const int4*)(aptr + k1 + 4);
            pb0 = *(const float4*)(bptr + k1);
            pb1 = *(const float4*)(bptr + k1 + 4);
            pscale = adelta * exp2f(-(float)aeptr[(k1 + scol) >> 5]);
        }
#pragma unroll
        for (int kk = 0; kk < TK; ++kk) {
            const float4 a0 = *(const float4*)&As[kk][ty * 4];
            const float4 a1 = *(const float4*)&As[kk][64 + ty * 4];
            const float4 b0 = *(const float4*)&Bs[kk][tx * 4];
            const float4 b1 = *(const float4*)&Bs[kk][64 + tx * 4];
            const double ad[8] = {(double)a0.x, (double)a0.y, (double)a0.z, (double)a0.w,
                                  (double)a1.x, (double)a1.y, (double)a1.z, (double)a1.w};
            const double bd[8] = {(double)b0.x, (double)b0.y, (double)b0.z, (double)b0.w,
                                  (double)b1.x, (double)b1.y, (double)b1.z, (double)b1.w};
#pragma unroll
            for (int i = 0; i < 8; ++i)
#pragma unroll
                for (int j = 0; j < 8; ++j)
                    acc[i][j] = fma(ad[i], bd[j], acc[i][j]);
        }
        __syncthreads();
    }
    const float4 bb0 = *(const float4*)&bias[n0 + tx * 4];
    const float4 bb1 = *(const float4*)&bias[n0 + 64 + tx * 4];
#pragma unroll
    for (int i = 0; i < 8; ++i) {
        const int row = m0 + ((i < 4) ? (ty * 4 + i) : (64 + ty * 4 + (i - 4)));
        float4 v0, v1;
        v0.x = (float)(acc[i][0] + (double)bb0.x); v0.y = (float)(acc[i][1] + (double)bb0.y);
        v0.z = (float)(acc[i][2] + (double)bb0.z); v0.w = (float)(acc[i][3] + (double)bb0.w);
        v1.x = (float)(acc[i][4] + (double)bb1.x); v1.y = (float)(acc[i][5] + (double)bb1.y);
        v1.z = (float)(acc[i][6] + (double)bb1.z); v1.w = (float)(acc[i][7] + (double)bb1.w);
        *(float4*)&y[(size_t)row * N + n0 + tx * 4] = v0;
        *(float4*)&y[(size_t)row * N + n0 + 64 + tx * 4] = v1;
    }
}

// ---------------- requant (known-good) ----------------

__global__ __launch_bounds__(256) void requant_kernel(
    float* __restrict__ y, float* __restrict__ odelta,
    float* __restrict__ oe, int N)
{
    const int t = blockIdx.x;
    const int tid = threadIdx.x;
    float* row = y + (size_t)t * N;
    float4 v[4];
    float cmax[4];
    float amax = 0.f;
#pragma unroll
    for (int j = 0; j < 4; ++j) {
        v[j] = *(const float4*)&row[(tid + j * 256) * 4];
        const float m01 = fmaxf(fabsf(v[j].x), fabsf(v[j].y));
        const float m23 = fmaxf(fabsf(v[j].z), fabsf(v[j].w));
        cmax[j] = fmaxf(m01, m23);
        amax = fmaxf(amax, cmax[j]);
    }
    __shared__ float red[256];
    red[tid] = amax;
    __syncthreads();
#pragma unroll
    for (int s = 128; s >= 1; s >>= 1) {
        if (tid < s) red[tid] = fmaxf(red[tid], red[tid + s]);
        __syncthreads();
    }
    const float absmax = red[0];
    const float delta = absmax / 127.0f;
    if (tid == 0) odelta[t] = delta;
    const int G = N >> 5;
#pragma unroll
    for (int j = 0; j < 4; ++j) {
        float gm = cmax[j];
        gm = fmaxf(gm, __shfl_xor(gm, 1));
        gm = fmaxf(gm, __shfl_xor(gm, 2));
        gm = fmaxf(gm, __shfl_xor(gm, 4));
        const float ratio = (delta * 127.0f) / fmaxf(gm, 1e-8f);
        const float rr = fmaxf(ratio, 1.0f);
        float e = floorf(log2f(rr));
        e = fminf(e, 15.0f);
        const float scale = delta * exp2f(-e);
        if ((tid & 7) == 0) oe[(size_t)t * G + (tid >> 3) + 32 * j] = e;
        const float den = fmaxf(scale, 1e-8f);
        float4 q;
        q.x = fminf(fmaxf(rintf(v[j].x / den), -127.f), 127.f);
        q.y = fminf(fmaxf(rintf(v[j].y / den), -127.f), 127.f);
        q.z = fminf(fmaxf(rintf(v[j].z / den), -127.f), 127.f);
        q.w = fminf(fmaxf(rintf(v[j].w / den), -127.f), 127.f);
        *(float4*)&row[(tid + j * 256) * 4] = q;
    }
}

// ---------------- launch ----------------

extern "C" void kernel_launch(void* const* d_in, const int* in_sizes, int n_in,
                              void* d_out, int out_size, void* d_ws, size_t ws_size,
                              hipStream_t stream) {
    const int*   xq     = (const int*)d_in[0];
    const float* xdelta = (const float*)d_in[1];
    const int*   xe     = (const int*)d_in[2];
    const float* W      = (const float*)d_in[3];
    const float* bias   = (const float*)d_in[4];

    const int M = in_sizes[1];            // 8192
    const int K = in_sizes[0] / M;        // 4096
    const int N = in_sizes[4];            // 4096

    float* out    = (float*)d_out;
    float* yq     = out;                  // holds f32 y, then q in-place
    float* odelta = out + (size_t)M * N;
    float* oe     = odelta + M;

    const size_t planeN = (size_t)N * K;
    const size_t szMK = (size_t)M * K;
    const size_t need = 4 * planeN + szMK + 4 * (size_t)N;

    if (ws_size >= need) {
        char* ws = (char*)d_ws;
        signed char* wp = (signed char*)ws;                    // 4 planes [N][K]
        signed char* q8 = (signed char*)(ws + 4 * planeN);     // [M][K]
        int*         Ee = (int*)(ws + 4 * planeN + szMK);      // [N]

        wprep_rowmax<<<dim3(N), dim3(256), 0, stream>>>(W, Ee, K);
        wprep_slice<<<dim3(N), dim3(256), 0, stream>>>(W, Ee, wp, planeN, K);
        xprep<<<dim3(M), dim3(256), 0, stream>>>(xq, q8, K);
        gemm_int<<<dim3(N / 64, M / 128), dim3(256), 0, stream>>>(
            q8, xe, xdelta, wp, Ee, bias, yq, M, N, K);
    } else {
        gemm_dq_kernel<<<dim3(N / TN, M / TM), dim3(256), 0, stream>>>(
            xq, xdelta, xe, W, bias, yq, M, N, K);
    }
    requant_kernel<<<dim3(M), dim3(256), 0, stream>>>(yq, odelta, oe, N);
}

// Round 5
// 1063.549 us; speedup vs baseline: 1.4334x; 1.4334x over previous
//
#include <hip/hip_runtime.h>

// GroupQLinear: dequant(int8 group-quant) -> GEMM -> bias -> group requant.
// e = floor(log2(absmax/gmax)) is DISCRETE -> y must be ~1e-7-accurate.
//
// All-integer scheme: X = q*2^(15-e) is an exact 22-bit int at the common
// per-token scale delta*2^-15 -> 3 balanced i8 digit planes (pre-split).
// W ~= W29*2^(E-29), W29 = rintf(w*2^(29-E)) -> 4 balanced i8 digit planes.
// 9 digit-pair products (digit-sum g<=3; g=4 terms ~1.5e-8 rel, dropped) via
// mfma_i32_32x32x32_i8, exact i32 accumulation over ALL of K. One f64 Horner
// combine in the epilogue. Planes stored in LDS-tile layout [K/16][rows][16B]
// so the GEMM stages via global_load_lds (no staging VALU, coalesced).

typedef __attribute__((ext_vector_type(4)))  int int32x4;
typedef __attribute__((ext_vector_type(16))) int int32x16;

__device__ __forceinline__ void gload16(const void* g, void* l) {
    __builtin_amdgcn_global_load_lds(
        (const __attribute__((address_space(1))) unsigned int*)g,
        (__attribute__((address_space(3))) unsigned int*)l,
        16, 0, 0);
}

// ---------------- prep kernels ----------------

__global__ __launch_bounds__(256) void wprep_rowmax(const float* __restrict__ W,
                                                    int* __restrict__ Eexp, int K) {
    const int o = blockIdx.x;
    const float* row = W + (size_t)o * K;
    float m = 0.f;
    for (int k = threadIdx.x; k < K; k += 256) m = fmaxf(m, fabsf(row[k]));
    __shared__ float red[256];
    red[threadIdx.x] = m;
    __syncthreads();
    for (int s = 128; s >= 1; s >>= 1) {
        if (threadIdx.x < s) red[threadIdx.x] = fmaxf(red[threadIdx.x], red[threadIdx.x + s]);
        __syncthreads();
    }
    if (threadIdx.x == 0) Eexp[o] = (red[0] > 0.f) ? ilogbf(red[0]) : 0;
}

// W planes: plane j holds byte (3-j) of C(W29), layout [K/16][N][16B].
__global__ __launch_bounds__(256) void wprep_planes(const float* __restrict__ W,
                                                    const int* __restrict__ Eexp,
                                                    signed char* __restrict__ Wp,
                                                    int N, int K) {
    const int k0 = blockIdx.x * 64;
    const int n0 = blockIdx.y * 64;
    const int t = threadIdx.x;
    const int r = t >> 2;
    const int kc = (t & 3) * 16;
    const int o = n0 + r;
    const int k = k0 + kc;
    const int E = Eexp[o];
    const float s = ldexpf(1.0f, 29 - E);
    const float* src = W + (size_t)o * K + k;
    const size_t wplane = (size_t)N * K;
    unsigned pl[4][4];
#pragma unroll
    for (int g4 = 0; g4 < 4; ++g4) {
        float4 wv = *(const float4*)(src + g4 * 4);
        const float v[4] = {wv.x, wv.y, wv.z, wv.w};
        unsigned C[4];
#pragma unroll
        for (int i = 0; i < 4; ++i) {
            int W29 = (int)rintf(v[i] * s);
            C[i] = ((unsigned)W29 + 0x80808080u) ^ 0x80808080u;
        }
#pragma unroll
        for (int b = 0; b < 4; ++b) {
            const unsigned sel = (unsigned)(((4 + b) << 8) | b);
            unsigned s01 = __builtin_amdgcn_perm(C[1], C[0], sel);
            unsigned s23 = __builtin_amdgcn_perm(C[3], C[2], sel);
            pl[3 - b][g4] = __builtin_amdgcn_perm(s23, s01, 0x05040100u);
        }
    }
    const size_t slab = ((size_t)(k >> 4) * N + o) * 16;
#pragma unroll
    for (int j = 0; j < 4; ++j)
        *(uint4*)(Wp + j * wplane + slab) =
            make_uint4(pl[j][0], pl[j][1], pl[j][2], pl[j][3]);
}

// X planes: plane p holds byte (2-p) of C(X), X = q*2^(15-e); layout [K/16][Ms][16B].
__global__ __launch_bounds__(256) void xprep_planes(const int* __restrict__ xq,
                                                    const int* __restrict__ xe,
                                                    signed char* __restrict__ Xp,
                                                    int mbase, int Ms, int K) {
    const int k0 = blockIdx.x * 64;
    const int mt = blockIdx.y * 64;
    const int t = threadIdx.x;
    const int r = t >> 2;
    const int kc = (t & 3) * 16;
    const int m = mbase + mt + r;   // absolute row
    const int k = k0 + kc;
    const int e = xe[(size_t)m * (K >> 5) + (k >> 5)];
    const int sh = 15 - e;
    const int* src = xq + (size_t)m * K + k;
    const size_t xplane = (size_t)Ms * K;
    unsigned pl[3][4];
#pragma unroll
    for (int g4 = 0; g4 < 4; ++g4) {
        int4 qv = *(const int4*)(src + g4 * 4);
        const int q[4] = {qv.x, qv.y, qv.z, qv.w};
        unsigned C[4];
#pragma unroll
        for (int i = 0; i < 4; ++i) {
            const int X = q[i] << sh;                      // exact, |X| <= 2^22
            C[i] = ((unsigned)X + 0x00808080u) ^ 0x00808080u;
        }
#pragma unroll
        for (int b = 0; b < 3; ++b) {
            const unsigned sel = (unsigned)(((4 + b) << 8) | b);
            unsigned s01 = __builtin_amdgcn_perm(C[1], C[0], sel);
            unsigned s23 = __builtin_amdgcn_perm(C[3], C[2], sel);
            pl[2 - b][g4] = __builtin_amdgcn_perm(s23, s01, 0x05040100u);
        }
    }
    const size_t slab = ((size_t)(k >> 4) * Ms + (mt + r)) * 16;
#pragma unroll
    for (int p = 0; p < 3; ++p)
        *(uint4*)(Xp + p * xplane + slab) =
            make_uint4(pl[p][0], pl[p][1], pl[p][2], pl[p][3]);
}

// ---------------- all-int GEMM with global_load_lds staging ----------------
// 256 thr = 4 waves; block tile 128m x 64o; BK=64 (two quant groups).
// wave tile 32m x 64o = 2 subtiles of 32x32. A-op = W digits (D rows = o),
// B-op = X digits (D cols = m).  LDS 40KB single-buffered:
//   X: 3 planes x [4 kb][128 rows][16B] = 24576 B   (sections XSEC)
//   W: 4 planes x [4 kb][ 64 rows][16B] = 16384 B   (sections WSEC)
// Staged as 40 wave-chunks of 1KB, linear: chunk c -> LDS byte c*1024.

#define XSEC(p) ((p) * 8192)
#define WSEC(j) (24576 + (j) * 4096)

__global__ __launch_bounds__(256, 2) void gemm_int2(
    const signed char* __restrict__ Xp,   // 3 planes [K/16][Ms][16]
    const float* __restrict__ xdelta,     // [M] absolute
    const signed char* __restrict__ Wp,   // 4 planes [K/16][N][16]
    const int* __restrict__ Eexp,         // [N]
    const float* __restrict__ bias,       // [N]
    float* __restrict__ y,                // [M][N] f32
    int Ms, int mbase, int N, int K)
{
    __shared__ alignas(16) char smem[40960];

    const int tid = threadIdx.x;
    const int m0 = blockIdx.y * 128;            // within stripe
    const int n0 = blockIdx.x * 64;
    const int w = tid >> 6, lane = tid & 63, lj = lane & 31, hi = lane >> 5;
    const int m_w = w * 32;

    const size_t xplane = (size_t)Ms * K;
    const size_t wplane = (size_t)N * K;

    // staging chunks: c = 4*i + w, i = 0..9
    const char* gp[10];
    unsigned ldso[10];
    long gstride[10];
#pragma unroll
    for (int i = 0; i < 10; ++i) {
        const int c = 4 * i + w;
        ldso[i] = (unsigned)c * 1024u;
        if (c < 24) {
            const int p = c >> 3, kb = (c >> 1) & 3, h = c & 1;
            gp[i] = (const char*)Xp + p * xplane + ((size_t)kb * Ms + m0 + 64 * h + lane) * 16;
            gstride[i] = (long)4 * Ms * 16;
        } else {
            const int cw = c - 24, j = cw >> 2, kb = cw & 3;
            gp[i] = (const char*)Wp + j * wplane + ((size_t)kb * N + n0 + lane) * 16;
            gstride[i] = (long)4 * N * 16;
        }
    }

    int32x16 acc[2][4];
#pragma unroll
    for (int s = 0; s < 2; ++s)
#pragma unroll
        for (int g = 0; g < 4; ++g)
#pragma unroll
            for (int r = 0; r < 16; ++r) acc[s][g][r] = 0;

    for (int kt = 0; kt < K; kt += 64) {
        __syncthreads();                 // LDS consumers done
#pragma unroll
        for (int i = 0; i < 10; ++i) {
            gload16(gp[i], smem + ldso[i]);
            gp[i] += gstride[i];
        }
        __syncthreads();                 // drains vmcnt, LDS ready
#pragma unroll
        for (int ks = 0; ks < 2; ++ks) {
            const int kbb = 2 * ks + hi;
            const int xro = (kbb * 128 + m_w + lj) * 16;
            int32x4 xf0 = *(const int32x4*)(smem + XSEC(0) + xro);
            int32x4 xf1 = *(const int32x4*)(smem + XSEC(1) + xro);
            int32x4 xf2 = *(const int32x4*)(smem + XSEC(2) + xro);
#pragma unroll
            for (int s = 0; s < 2; ++s) {
                const int wro = (kbb * 64 + 32 * s + lj) * 16;
                int32x4 wf0 = *(const int32x4*)(smem + WSEC(0) + wro);
                int32x4 wf1 = *(const int32x4*)(smem + WSEC(1) + wro);
                int32x4 wf2 = *(const int32x4*)(smem + WSEC(2) + wro);
                int32x4 wf3 = *(const int32x4*)(smem + WSEC(3) + wro);
                acc[s][0] = __builtin_amdgcn_mfma_i32_32x32x32_i8(wf0, xf0, acc[s][0], 0, 0, 0);
                acc[s][1] = __builtin_amdgcn_mfma_i32_32x32x32_i8(wf0, xf1, acc[s][1], 0, 0, 0);
                acc[s][1] = __builtin_amdgcn_mfma_i32_32x32x32_i8(wf1, xf0, acc[s][1], 0, 0, 0);
                acc[s][2] = __builtin_amdgcn_mfma_i32_32x32x32_i8(wf0, xf2, acc[s][2], 0, 0, 0);
                acc[s][2] = __builtin_amdgcn_mfma_i32_32x32x32_i8(wf1, xf1, acc[s][2], 0, 0, 0);
                acc[s][2] = __builtin_amdgcn_mfma_i32_32x32x32_i8(wf2, xf0, acc[s][2], 0, 0, 0);
                acc[s][3] = __builtin_amdgcn_mfma_i32_32x32x32_i8(wf1, xf2, acc[s][3], 0, 0, 0);
                acc[s][3] = __builtin_amdgcn_mfma_i32_32x32x32_i8(wf2, xf1, acc[s][3], 0, 0, 0);
                acc[s][3] = __builtin_amdgcn_mfma_i32_32x32x32_i8(wf3, xf0, acc[s][3], 0, 0, 0);
            }
        }
    }

    // epilogue: f64 Horner combine, scale, transpose via LDS, coalesced store
    __syncthreads();
    const double delta_d = (double)xdelta[mbase + m0 + m_w + lj];
    float* tw = (float*)(void*)smem + w * 1056;   // 32x33 f32 per wave
#pragma unroll
    for (int s = 0; s < 2; ++s) {
#pragma unroll
        for (int r = 0; r < 16; ++r) {
            const int ol = (r & 3) + 8 * (r >> 2) + 4 * hi;
            const int o = n0 + 32 * s + ol;
            const double c8 = 1.0 / 256.0;
            double h = (double)acc[s][0][r]
                     + c8 * ((double)acc[s][1][r]
                     + c8 * ((double)acc[s][2][r]
                     + c8 *  (double)acc[s][3][r]));
            double v = fma(ldexp(delta_d, Eexp[o] - 4), h, (double)bias[o]);
            tw[ol * 33 + lj] = (float)v;
        }
        __syncthreads();
#pragma unroll
        for (int it = 0; it < 16; ++it) {
            const int mr = 2 * it + hi;
            y[(size_t)(mbase + m0 + m_w + mr) * N + (n0 + 32 * s + lj)] = tw[lj * 33 + mr];
        }
        __syncthreads();
    }
}

// ---------------- fallback f64 GEMM (known-good, r2) ----------------

#define TM 128
#define TN 128
#define TK 16
#define LDT 132

__global__ __launch_bounds__(256, 2) void gemm_dq_kernel(
    const int* __restrict__ xq, const float* __restrict__ xdelta,
    const int* __restrict__ xe, const float* __restrict__ W,
    const float* __restrict__ bias, float* __restrict__ y,
    int M, int N, int K)
{
    __shared__ float As[TK][LDT];
    __shared__ float Bs[TK][LDT];
    const int tid = threadIdx.x;
    const int tx = tid & 15;
    const int ty = tid >> 4;
    const int m0 = blockIdx.y * TM;
    const int n0 = blockIdx.x * TN;
    const int srow = tid >> 1;
    const int scol = (tid & 1) * 8;
    const int Kg = K >> 5;
    const int*   aptr = xq + (size_t)(m0 + srow) * K + scol;
    const float* bptr = W  + (size_t)(n0 + srow) * K + scol;
    const float  adelta = xdelta[m0 + srow];
    const int*   aeptr  = xe + (size_t)(m0 + srow) * Kg;
    int4 pa0, pa1; float4 pb0, pb1; float pscale;
    pa0 = *(const int4*)(aptr);
    pa1 = *(const int4*)(aptr + 4);
    pb0 = *(const float4*)(bptr);
    pb1 = *(const float4*)(bptr + 4);
    pscale = adelta * exp2f(-(float)aeptr[scol >> 5]);
    double acc[8][8];
#pragma unroll
    for (int i = 0; i < 8; ++i)
#pragma unroll
        for (int j = 0; j < 8; ++j) acc[i][j] = 0.0;
    for (int kt = 0; kt < K; kt += TK) {
        {
            float* as = &As[scol][srow];
            as[0*LDT] = (float)pa0.x * pscale; as[1*LDT] = (float)pa0.y * pscale;
            as[2*LDT] = (float)pa0.z * pscale; as[3*LDT] = (float)pa0.w * pscale;
            as[4*LDT] = (float)pa1.x * pscale; as[5*LDT] = (float)pa1.y * pscale;
            as[6*LDT] = (float)pa1.z * pscale; as[7*LDT] = (float)pa1.w * pscale;
            float* bs = &Bs[scol][srow];
            bs[0*LDT] = pb0.x; bs[1*LDT] = pb0.y; bs[2*LDT] = pb0.z; bs[3*LDT] = pb0.w;
            bs[4*LDT] = pb1.x; bs[5*LDT] = pb1.y; bs[6*LDT] = pb1.z; bs[7*LDT] = pb1.w;
        }
        __syncthreads();
        if (kt + TK < K) {
            const int k1 = kt + TK;
            pa0 = *(const int4*)(aptr + k1);
            pa1 = *(const int4*)(aptr + k1 + 4);
            pb0 = *(const float4*)(bptr + k1);
            pb1 = *(const float4*)(bptr + k1 + 4);
            pscale = adelta * exp2f(-(float)aeptr[(k1 + scol) >> 5]);
        }
#pragma unroll
        for (int kk = 0; kk < TK; ++kk) {
            const float4 a0 = *(const float4*)&As[kk][ty * 4];
            const float4 a1 = *(const float4*)&As[kk][64 + ty * 4];
            const float4 b0 = *(const float4*)&Bs[kk][tx * 4];
            const float4 b1 = *(const float4*)&Bs[kk][64 + tx * 4];
            const double ad[8] = {(double)a0.x, (double)a0.y, (double)a0.z, (double)a0.w,
                                  (double)a1.x, (double)a1.y, (double)a1.z, (double)a1.w};
            const double bd[8] = {(double)b0.x, (double)b0.y, (double)b0.z, (double)b0.w,
                                  (double)b1.x, (double)b1.y, (double)b1.z, (double)b1.w};
#pragma unroll
            for (int i = 0; i < 8; ++i)
#pragma unroll
                for (int j = 0; j < 8; ++j)
                    acc[i][j] = fma(ad[i], bd[j], acc[i][j]);
        }
        __syncthreads();
    }
    const float4 bb0 = *(const float4*)&bias[n0 + tx * 4];
    const float4 bb1 = *(const float4*)&bias[n0 + 64 + tx * 4];
#pragma unroll
    for (int i = 0; i < 8; ++i) {
        const int row = m0 + ((i < 4) ? (ty * 4 + i) : (64 + ty * 4 + (i - 4)));
        float4 v0, v1;
        v0.x = (float)(acc[i][0] + (double)bb0.x); v0.y = (float)(acc[i][1] + (double)bb0.y);
        v0.z = (float)(acc[i][2] + (double)bb0.z); v0.w = (float)(acc[i][3] + (double)bb0.w);
        v1.x = (float)(acc[i][4] + (double)bb1.x); v1.y = (float)(acc[i][5] + (double)bb1.y);
        v1.z = (float)(acc[i][6] + (double)bb1.z); v1.w = (float)(acc[i][7] + (double)bb1.w);
        *(float4*)&y[(size_t)row * N + n0 + tx * 4] = v0;
        *(float4*)&y[(size_t)row * N + n0 + 64 + tx * 4] = v1;
    }
}

// ---------------- requant (known-good) ----------------

__global__ __launch_bounds__(256) void requant_kernel(
    float* __restrict__ y, float* __restrict__ odelta,
    float* __restrict__ oe, int N)
{
    const int t = blockIdx.x;
    const int tid = threadIdx.x;
    float* row = y + (size_t)t * N;
    float4 v[4];
    float cmax[4];
    float amax = 0.f;
#pragma unroll
    for (int j = 0; j < 4; ++j) {
        v[j] = *(const float4*)&row[(tid + j * 256) * 4];
        const float m01 = fmaxf(fabsf(v[j].x), fabsf(v[j].y));
        const float m23 = fmaxf(fabsf(v[j].z), fabsf(v[j].w));
        cmax[j] = fmaxf(m01, m23);
        amax = fmaxf(amax, cmax[j]);
    }
    __shared__ float red[256];
    red[tid] = amax;
    __syncthreads();
#pragma unroll
    for (int s = 128; s >= 1; s >>= 1) {
        if (tid < s) red[tid] = fmaxf(red[tid], red[tid + s]);
        __syncthreads();
    }
    const float absmax = red[0];
    const float delta = absmax / 127.0f;
    if (tid == 0) odelta[t] = delta;
    const int G = N >> 5;
#pragma unroll
    for (int j = 0; j < 4; ++j) {
        float gm = cmax[j];
        gm = fmaxf(gm, __shfl_xor(gm, 1));
        gm = fmaxf(gm, __shfl_xor(gm, 2));
        gm = fmaxf(gm, __shfl_xor(gm, 4));
        const float ratio = (delta * 127.0f) / fmaxf(gm, 1e-8f);
        const float rr = fmaxf(ratio, 1.0f);
        float e = floorf(log2f(rr));
        e = fminf(e, 15.0f);
        const float scale = delta * exp2f(-e);
        if ((tid & 7) == 0) oe[(size_t)t * G + (tid >> 3) + 32 * j] = e;
        const float den = fmaxf(scale, 1e-8f);
        float4 q;
        q.x = fminf(fmaxf(rintf(v[j].x / den), -127.f), 127.f);
        q.y = fminf(fmaxf(rintf(v[j].y / den), -127.f), 127.f);
        q.z = fminf(fmaxf(rintf(v[j].z / den), -127.f), 127.f);
        q.w = fminf(fmaxf(rintf(v[j].w / den), -127.f), 127.f);
        *(float4*)&row[(tid + j * 256) * 4] = q;
    }
}

// ---------------- launch ----------------

extern "C" void kernel_launch(void* const* d_in, const int* in_sizes, int n_in,
                              void* d_out, int out_size, void* d_ws, size_t ws_size,
                              hipStream_t stream) {
    const int*   xq     = (const int*)d_in[0];
    const float* xdelta = (const float*)d_in[1];
    const int*   xe     = (const int*)d_in[2];
    const float* W      = (const float*)d_in[3];
    const float* bias   = (const float*)d_in[4];

    const int M = in_sizes[1];            // 8192
    const int K = in_sizes[0] / M;        // 4096
    const int N = in_sizes[4];            // 4096

    float* out    = (float*)d_out;
    float* yq     = out;                  // holds f32 y, then q in-place
    float* odelta = out + (size_t)M * N;
    float* oe     = odelta + M;

    const int Ms = M / 2;                 // stripe rows
    const size_t wplaneSz = (size_t)N * K;
    const size_t xplaneSz = (size_t)Ms * K;
    const size_t need = 4 * wplaneSz + 3 * xplaneSz + 4 * (size_t)N;

    if ((M % 256) == 0 && (N % 64) == 0 && (K % 64) == 0 && ws_size >= need) {
        char* ws = (char*)d_ws;
        signed char* Wp = (signed char*)ws;                       // 4 planes [K/16][N][16]
        signed char* Xp = (signed char*)(ws + 4 * wplaneSz);      // 3 planes [K/16][Ms][16]
        int*         Ee = (int*)(ws + 4 * wplaneSz + 3 * xplaneSz);

        wprep_rowmax<<<dim3(N), dim3(256), 0, stream>>>(W, Ee, K);
        wprep_planes<<<dim3(K / 64, N / 64), dim3(256), 0, stream>>>(W, Ee, Wp, N, K);
        for (int st = 0; st < 2; ++st) {
            const int mbase = st * Ms;
            xprep_planes<<<dim3(K / 64, Ms / 64), dim3(256), 0, stream>>>(
                xq, xe, Xp, mbase, Ms, K);
            gemm_int2<<<dim3(N / 64, Ms / 128), dim3(256), 0, stream>>>(
                Xp, xdelta, Wp, Ee, bias, yq, Ms, mbase, N, K);
        }
    } else {
        gemm_dq_kernel<<<dim3(N / TN, M / TM), dim3(256), 0, stream>>>(
            xq, xdelta, xe, W, bias, yq, M, N, K);
    }
    requant_kernel<<<dim3(M), dim3(256), 0, stream>>>(yq, odelta, oe, N);
}

// Round 6
// 910.000 us; speedup vs baseline: 1.6753x; 1.1687x over previous
//
#include <hip/hip_runtime.h>

// GroupQLinear: dequant(int8 group-quant) -> GEMM -> bias -> group requant.
// e = floor(log2(absmax/gmax)) is DISCRETE -> y must be ~1e-7-accurate.
//
// All-integer scheme: X' = q*2^(Cm-e) (Cm = emin_row+8) is an exact <=2^15 int
// at the common per-row scale delta*2^-Cm -> 2 balanced i8 digit planes.
// W ~= W29*2^(E-29), W29 = rintf(w*2^(29-E)) -> 4 balanced i8 digit planes.
// 7 digit-pair products (weight >= 2^8 of 2^32) via mfma_i32_32x32x32_i8,
// exact i32 accumulation over ALL of K. One f64 Horner combine in epilogue.
// Guard: if any row has e-span > 8, fall back to the proven 3-plane/9-pair
// kernel (flag-gated on device). GEMM is double-buffered with counted vmcnt.

typedef __attribute__((ext_vector_type(4)))  int int32x4;
typedef __attribute__((ext_vector_type(16))) int int32x16;

__device__ __forceinline__ void gload16(const void* g, void* l) {
    __builtin_amdgcn_global_load_lds(
        (const __attribute__((address_space(1))) unsigned int*)g,
        (__attribute__((address_space(3))) unsigned int*)l,
        16, 0, 0);
}

// ---------------- prep kernels ----------------

__global__ __launch_bounds__(256) void wprep_rowmax(const float* __restrict__ W,
                                                    int* __restrict__ Eexp, int K) {
    const int o = blockIdx.x;
    const float* row = W + (size_t)o * K;
    float m = 0.f;
    for (int k = threadIdx.x; k < K; k += 256) m = fmaxf(m, fabsf(row[k]));
    __shared__ float red[256];
    red[threadIdx.x] = m;
    __syncthreads();
    for (int s = 128; s >= 1; s >>= 1) {
        if (threadIdx.x < s) red[threadIdx.x] = fmaxf(red[threadIdx.x], red[threadIdx.x + s]);
        __syncthreads();
    }
    if (threadIdx.x == 0) Eexp[o] = (red[0] > 0.f) ? ilogbf(red[0]) : 0;
}

// W planes: plane j holds balanced byte (3-j) of W29, layout [K/16][N][16B].
__global__ __launch_bounds__(256) void wprep_planes(const float* __restrict__ W,
                                                    const int* __restrict__ Eexp,
                                                    signed char* __restrict__ Wp,
                                                    int N, int K) {
    const int k0 = blockIdx.x * 64;
    const int n0 = blockIdx.y * 64;
    const int t = threadIdx.x;
    const int r = t >> 2;
    const int kc = (t & 3) * 16;
    const int o = n0 + r;
    const int k = k0 + kc;
    const int E = Eexp[o];
    const float s = ldexpf(1.0f, 29 - E);
    const float* src = W + (size_t)o * K + k;
    const size_t wplane = (size_t)N * K;
    unsigned pl[4][4];
#pragma unroll
    for (int g4 = 0; g4 < 4; ++g4) {
        float4 wv = *(const float4*)(src + g4 * 4);
        const float v[4] = {wv.x, wv.y, wv.z, wv.w};
        unsigned C[4];
#pragma unroll
        for (int i = 0; i < 4; ++i) {
            int W29 = (int)rintf(v[i] * s);
            C[i] = ((unsigned)W29 + 0x80808080u) ^ 0x80808080u;
        }
#pragma unroll
        for (int b = 0; b < 4; ++b) {
            const unsigned sel = (unsigned)(((4 + b) << 8) | b);
            unsigned s01 = __builtin_amdgcn_perm(C[1], C[0], sel);
            unsigned s23 = __builtin_amdgcn_perm(C[3], C[2], sel);
            pl[3 - b][g4] = __builtin_amdgcn_perm(s23, s01, 0x05040100u);
        }
    }
    const size_t slab = ((size_t)(k >> 4) * N + o) * 16;
#pragma unroll
    for (int j = 0; j < 4; ++j)
        *(uint4*)(Wp + j * wplane + slab) =
            make_uint4(pl[j][0], pl[j][1], pl[j][2], pl[j][3]);
}

// per-row e-span guard: Cm[m] = emin+8; flag=1 if span > 8 anywhere.
__global__ __launch_bounds__(128) void eguard(const int* __restrict__ xe,
                                              int* __restrict__ Cm,
                                              int* __restrict__ flag, int Kg) {
    const int m = blockIdx.x;
    const int t = threadIdx.x;
    int emin = 1 << 30, emax = -(1 << 30);
    for (int g = t; g < Kg; g += 128) {
        const int e = xe[(size_t)m * Kg + g];
        emin = min(emin, e);
        emax = max(emax, e);
    }
#pragma unroll
    for (int off = 32; off >= 1; off >>= 1) {
        emin = min(emin, __shfl_down(emin, off));
        emax = max(emax, __shfl_down(emax, off));
    }
    __shared__ int sm[2][2];
    if ((t & 63) == 0) { sm[t >> 6][0] = emin; sm[t >> 6][1] = emax; }
    __syncthreads();
    if (t == 0) {
        emin = min(sm[0][0], sm[1][0]);
        emax = max(sm[0][1], sm[1][1]);
        Cm[m] = emin + 8;
        if (emax - emin > 8) atomicOr(flag, 1);
    }
}

// X planes, dual encoding. flag==0: 2 planes of X' = q<<(Cm-e) (shift in [0,8]).
// flag!=0: 3 planes of X = q<<(15-e) (r5 encoding). Layout [K/16][Ms][16B].
__global__ __launch_bounds__(256) void xprep2(const int* __restrict__ xq,
                                              const int* __restrict__ xe,
                                              const int* __restrict__ Cm,
                                              const int* __restrict__ flag,
                                              signed char* __restrict__ Xp,
                                              int mbase, int Ms, int K) {
    const int k0 = blockIdx.x * 64, mt = blockIdx.y * 64;
    const int t = threadIdx.x, r = t >> 2, kc = (t & 3) * 16;
    const int m = mbase + mt + r, k = k0 + kc;
    const int e = xe[(size_t)m * (K >> 5) + (k >> 5)];
    const int* src = xq + (size_t)m * K + k;
    const size_t xplane = (size_t)Ms * K;
    const size_t slab = ((size_t)(k >> 4) * Ms + (mt + r)) * 16;
    if (*flag == 0) {
        const int sh = Cm[m] - e;            // [0,8]; |X'| <= 127*256
        unsigned p0[4], p1[4];
#pragma unroll
        for (int g4 = 0; g4 < 4; ++g4) {
            int4 qv = *(const int4*)(src + g4 * 4);
            const int qa[4] = {qv.x, qv.y, qv.z, qv.w};
            unsigned b0 = 0, b1 = 0;
#pragma unroll
            for (int i = 0; i < 4; ++i) {
                const int X = qa[i] << sh;
                const int d0 = (X + 128) >> 8;       // balanced hi digit
                const int d1 = X - (d0 << 8);        // [-128,127]
                b0 |= (unsigned)(d0 & 0xFF) << (8 * i);
                b1 |= (unsigned)(d1 & 0xFF) << (8 * i);
            }
            p0[g4] = b0; p1[g4] = b1;
        }
        *(uint4*)(Xp + slab)          = make_uint4(p0[0], p0[1], p0[2], p0[3]);
        *(uint4*)(Xp + xplane + slab) = make_uint4(p1[0], p1[1], p1[2], p1[3]);
    } else {
        const int sh = 15 - e;
        unsigned pl[3][4];
#pragma unroll
        for (int g4 = 0; g4 < 4; ++g4) {
            int4 qv = *(const int4*)(src + g4 * 4);
            const int qa[4] = {qv.x, qv.y, qv.z, qv.w};
            unsigned C[4];
#pragma unroll
            for (int i = 0; i < 4; ++i) {
                const int X = qa[i] << sh;
                C[i] = ((unsigned)X + 0x00808080u) ^ 0x00808080u;
            }
#pragma unroll
            for (int b = 0; b < 3; ++b) {
                const unsigned sel = (unsigned)(((4 + b) << 8) | b);
                unsigned s01 = __builtin_amdgcn_perm(C[1], C[0], sel);
                unsigned s23 = __builtin_amdgcn_perm(C[3], C[2], sel);
                pl[2 - b][g4] = __builtin_amdgcn_perm(s23, s01, 0x05040100u);
            }
        }
#pragma unroll
        for (int p = 0; p < 3; ++p)
            *(uint4*)(Xp + p * xplane + slab) =
                make_uint4(pl[p][0], pl[p][1], pl[p][2], pl[p][3]);
    }
}

// ---------------- 7-pair double-buffered GEMM (flag==0 path) ----------------
// 256 thr = 4 waves; block 128m x 64o; BK=64. wave 32m x 64o (2 subtiles).
// LDS buffer 32KB: X 2 planes x [4kb][128][16] (16KB) + W 4 x [4kb][64][16]
// (16KB); double-buffered = 64KB -> 2 blocks/CU. 32 linear 1KB chunks/tile,
// 8 per wave (i<4 -> X, i>=4 -> W). Counted vmcnt(8), raw barriers, setprio.

#define BUFSZ 32768
#define XS(p) ((p) * 8192)
#define WS(j) (16384 + (j) * 4096)

__global__ __launch_bounds__(256, 2) void gemm_int3(
    const signed char* __restrict__ Xp,   // 2 planes [K/16][Ms][16]
    const float* __restrict__ xdelta,     // [M] absolute
    const int* __restrict__ Cm,           // [M]
    const signed char* __restrict__ Wp,   // 4 planes [K/16][N][16]
    const int* __restrict__ Eexp,         // [N]
    const float* __restrict__ bias,       // [N]
    const int* __restrict__ flag,
    float* __restrict__ y,                // [M][N] f32
    int Ms, int mbase, int N, int K)
{
    if (*flag != 0) return;
    __shared__ alignas(16) char smem[2 * BUFSZ];

    const int tid = threadIdx.x;
    const int m0 = blockIdx.y * 128;
    const int n0 = blockIdx.x * 64;
    const int w = tid >> 6, lane = tid & 63, lj = lane & 31, hi = lane >> 5;
    const int m_w = w * 32;

    const size_t xplane = (size_t)Ms * K;
    const size_t wplane = (size_t)N * K;

    const char* gp[8];
    unsigned lo[8];
    long gs[8];
#pragma unroll
    for (int i = 0; i < 8; ++i) {
        const int c = 4 * i + w;
        lo[i] = (unsigned)c * 1024u;
        if (i < 4) {
            const int p = c >> 3, kb = (c >> 1) & 3, h = c & 1;
            gp[i] = (const char*)Xp + p * xplane + ((size_t)kb * Ms + m0 + 64 * h + lane) * 16;
            gs[i] = (long)4 * Ms * 16;
        } else {
            const int cw = c - 16, j = cw >> 2, kb = cw & 3;
            gp[i] = (const char*)Wp + j * wplane + ((size_t)kb * N + n0 + lane) * 16;
            gs[i] = (long)4 * N * 16;
        }
    }

    int32x16 acc[2][4];
#pragma unroll
    for (int s = 0; s < 2; ++s)
#pragma unroll
        for (int g = 0; g < 4; ++g)
#pragma unroll
            for (int r = 0; r < 16; ++r) acc[s][g][r] = 0;

    const int NT = K / 64;
    // prologue: tile 0 -> buf0
#pragma unroll
    for (int i = 0; i < 8; ++i) gload16(gp[i], smem + lo[i]);

    for (int t = 0; t < NT; ++t) {
        const char* sb = smem + (t & 1) * BUFSZ;
        if (t + 1 < NT) {
            char* db = smem + ((t + 1) & 1) * BUFSZ;
#pragma unroll
            for (int i = 0; i < 8; ++i) {
                gp[i] += gs[i];
                gload16(gp[i], db + lo[i]);
            }
            asm volatile("s_waitcnt vmcnt(8)" ::: "memory");   // tile t landed
        } else {
            asm volatile("s_waitcnt vmcnt(0)" ::: "memory");
        }
        __builtin_amdgcn_sched_barrier(0);
        __builtin_amdgcn_s_barrier();                          // tile t visible
        __builtin_amdgcn_sched_barrier(0);
        __builtin_amdgcn_s_setprio(1);
#pragma unroll
        for (int ks = 0; ks < 2; ++ks) {
            const int kbb = 2 * ks + hi;
            const int xro = (kbb * 128 + m_w + lj) * 16;
            int32x4 xf0 = *(const int32x4*)(sb + XS(0) + xro);
            int32x4 xf1 = *(const int32x4*)(sb + XS(1) + xro);
#pragma unroll
            for (int s = 0; s < 2; ++s) {
                const int wro = (kbb * 64 + 32 * s + lj) * 16;
                int32x4 wf0 = *(const int32x4*)(sb + WS(0) + wro);
                int32x4 wf1 = *(const int32x4*)(sb + WS(1) + wro);
                int32x4 wf2 = *(const int32x4*)(sb + WS(2) + wro);
                int32x4 wf3 = *(const int32x4*)(sb + WS(3) + wro);
                acc[s][0] = __builtin_amdgcn_mfma_i32_32x32x32_i8(wf0, xf0, acc[s][0], 0, 0, 0);
                acc[s][1] = __builtin_amdgcn_mfma_i32_32x32x32_i8(wf0, xf1, acc[s][1], 0, 0, 0);
                acc[s][1] = __builtin_amdgcn_mfma_i32_32x32x32_i8(wf1, xf0, acc[s][1], 0, 0, 0);
                acc[s][2] = __builtin_amdgcn_mfma_i32_32x32x32_i8(wf1, xf1, acc[s][2], 0, 0, 0);
                acc[s][2] = __builtin_amdgcn_mfma_i32_32x32x32_i8(wf2, xf0, acc[s][2], 0, 0, 0);
                acc[s][3] = __builtin_amdgcn_mfma_i32_32x32x32_i8(wf2, xf1, acc[s][3], 0, 0, 0);
                acc[s][3] = __builtin_amdgcn_mfma_i32_32x32x32_i8(wf3, xf0, acc[s][3], 0, 0, 0);
            }
        }
        __builtin_amdgcn_s_setprio(0);
        __builtin_amdgcn_s_barrier();                          // reads done
        __builtin_amdgcn_sched_barrier(0);
    }

    // epilogue: f64 Horner combine, scale, transpose via LDS, coalesced store
    const double delta_d = (double)xdelta[mbase + m0 + m_w + lj];
    const int Cmv = Cm[mbase + m0 + m_w + lj];
    float* tw = (float*)(void*)smem + w * 1056;   // 32x33 f32 per wave
#pragma unroll
    for (int s = 0; s < 2; ++s) {
#pragma unroll
        for (int r = 0; r < 16; ++r) {
            const int ol = (r & 3) + 8 * (r >> 2) + 4 * hi;
            const int o = n0 + 32 * s + ol;
            const double c8 = 1.0 / 256.0;
            double h = (double)acc[s][0][r]
                     + c8 * ((double)acc[s][1][r]
                     + c8 * ((double)acc[s][2][r]
                     + c8 *  (double)acc[s][3][r]));
            double v = fma(ldexp(delta_d, Eexp[o] + 3 - Cmv), h, (double)bias[o]);
            tw[ol * 33 + lj] = (float)v;
        }
        __syncthreads();
#pragma unroll
        for (int it = 0; it < 16; ++it) {
            const int mr = 2 * it + hi;
            y[(size_t)(mbase + m0 + m_w + mr) * N + (n0 + 32 * s + lj)] = tw[lj * 33 + mr];
        }
        __syncthreads();
    }
}

// ---------------- 9-pair fallback GEMM (flag!=0 path, r5-proven) ----------------

#define XSEC(p) ((p) * 8192)
#define WSEC(j) (24576 + (j) * 4096)

__global__ __launch_bounds__(256, 2) void gemm_int2(
    const signed char* __restrict__ Xp,   // 3 planes [K/16][Ms][16]
    const float* __restrict__ xdelta,
    const signed char* __restrict__ Wp,   // 4 planes [K/16][N][16]
    const int* __restrict__ Eexp,
    const float* __restrict__ bias,
    const int* __restrict__ flag,
    float* __restrict__ y,
    int Ms, int mbase, int N, int K)
{
    if (*flag == 0) return;
    __shared__ alignas(16) char smem[40960];

    const int tid = threadIdx.x;
    const int m0 = blockIdx.y * 128;
    const int n0 = blockIdx.x * 64;
    const int w = tid >> 6, lane = tid & 63, lj = lane & 31, hi = lane >> 5;
    const int m_w = w * 32;

    const size_t xplane = (size_t)Ms * K;
    const size_t wplane = (size_t)N * K;

    const char* gp[10];
    unsigned ldso[10];
    long gstride[10];
#pragma unroll
    for (int i = 0; i < 10; ++i) {
        const int c = 4 * i + w;
        ldso[i] = (unsigned)c * 1024u;
        if (c < 24) {
            const int p = c >> 3, kb = (c >> 1) & 3, h = c & 1;
            gp[i] = (const char*)Xp + p * xplane + ((size_t)kb * Ms + m0 + 64 * h + lane) * 16;
            gstride[i] = (long)4 * Ms * 16;
        } else {
            const int cw = c - 24, j = cw >> 2, kb = cw & 3;
            gp[i] = (const char*)Wp + j * wplane + ((size_t)kb * N + n0 + lane) * 16;
            gstride[i] = (long)4 * N * 16;
        }
    }

    int32x16 acc[2][4];
#pragma unroll
    for (int s = 0; s < 2; ++s)
#pragma unroll
        for (int g = 0; g < 4; ++g)
#pragma unroll
            for (int r = 0; r < 16; ++r) acc[s][g][r] = 0;

    for (int kt = 0; kt < K; kt += 64) {
        __syncthreads();
#pragma unroll
        for (int i = 0; i < 10; ++i) {
            gload16(gp[i], smem + ldso[i]);
            gp[i] += gstride[i];
        }
        __syncthreads();
#pragma unroll
        for (int ks = 0; ks < 2; ++ks) {
            const int kbb = 2 * ks + hi;
            const int xro = (kbb * 128 + m_w + lj) * 16;
            int32x4 xf0 = *(const int32x4*)(smem + XSEC(0) + xro);
            int32x4 xf1 = *(const int32x4*)(smem + XSEC(1) + xro);
            int32x4 xf2 = *(const int32x4*)(smem + XSEC(2) + xro);
#pragma unroll
            for (int s = 0; s < 2; ++s) {
                const int wro = (kbb * 64 + 32 * s + lj) * 16;
                int32x4 wf0 = *(const int32x4*)(smem + WSEC(0) + wro);
                int32x4 wf1 = *(const int32x4*)(smem + WSEC(1) + wro);
                int32x4 wf2 = *(const int32x4*)(smem + WSEC(2) + wro);
                int32x4 wf3 = *(const int32x4*)(smem + WSEC(3) + wro);
                acc[s][0] = __builtin_amdgcn_mfma_i32_32x32x32_i8(wf0, xf0, acc[s][0], 0, 0, 0);
                acc[s][1] = __builtin_amdgcn_mfma_i32_32x32x32_i8(wf0, xf1, acc[s][1], 0, 0, 0);
                acc[s][1] = __builtin_amdgcn_mfma_i32_32x32x32_i8(wf1, xf0, acc[s][1], 0, 0, 0);
                acc[s][2] = __builtin_amdgcn_mfma_i32_32x32x32_i8(wf0, xf2, acc[s][2], 0, 0, 0);
                acc[s][2] = __builtin_amdgcn_mfma_i32_32x32x32_i8(wf1, xf1, acc[s][2], 0, 0, 0);
                acc[s][2] = __builtin_amdgcn_mfma_i32_32x32x32_i8(wf2, xf0, acc[s][2], 0, 0, 0);
                acc[s][3] = __builtin_amdgcn_mfma_i32_32x32x32_i8(wf1, xf2, acc[s][3], 0, 0, 0);
                acc[s][3] = __builtin_amdgcn_mfma_i32_32x32x32_i8(wf2, xf1, acc[s][3], 0, 0, 0);
                acc[s][3] = __builtin_amdgcn_mfma_i32_32x32x32_i8(wf3, xf0, acc[s][3], 0, 0, 0);
            }
        }
    }

    __syncthreads();
    const double delta_d = (double)xdelta[mbase + m0 + m_w + lj];
    float* tw = (float*)(void*)smem + w * 1056;
#pragma unroll
    for (int s = 0; s < 2; ++s) {
#pragma unroll
        for (int r = 0; r < 16; ++r) {
            const int ol = (r & 3) + 8 * (r >> 2) + 4 * hi;
            const int o = n0 + 32 * s + ol;
            const double c8 = 1.0 / 256.0;
            double h = (double)acc[s][0][r]
                     + c8 * ((double)acc[s][1][r]
                     + c8 * ((double)acc[s][2][r]
                     + c8 *  (double)acc[s][3][r]));
            double v = fma(ldexp(delta_d, Eexp[o] - 4), h, (double)bias[o]);
            tw[ol * 33 + lj] = (float)v;
        }
        __syncthreads();
#pragma unroll
        for (int it = 0; it < 16; ++it) {
            const int mr = 2 * it + hi;
            y[(size_t)(mbase + m0 + m_w + mr) * N + (n0 + 32 * s + lj)] = tw[lj * 33 + mr];
        }
        __syncthreads();
    }
}

// ---------------- fallback f64 GEMM (ws too small; r2-proven) ----------------

#define TM 128
#define TN 128
#define TK 16
#define LDT 132

__global__ __launch_bounds__(256, 2) void gemm_dq_kernel(
    const int* __restrict__ xq, const float* __restrict__ xdelta,
    const int* __restrict__ xe, const float* __restrict__ W,
    const float* __restrict__ bias, float* __restrict__ y,
    int M, int N, int K)
{
    __shared__ float As[TK][LDT];
    __shared__ float Bs[TK][LDT];
    const int tid = threadIdx.x;
    const int tx = tid & 15;
    const int ty = tid >> 4;
    const int m0 = blockIdx.y * TM;
    const int n0 = blockIdx.x * TN;
    const int srow = tid >> 1;
    const int scol = (tid & 1) * 8;
    const int Kg = K >> 5;
    const int*   aptr = xq + (size_t)(m0 + srow) * K + scol;
    const float* bptr = W  + (size_t)(n0 + srow) * K + scol;
    const float  adelta = xdelta[m0 + srow];
    const int*   aeptr  = xe + (size_t)(m0 + srow) * Kg;
    int4 pa0, pa1; float4 pb0, pb1; float pscale;
    pa0 = *(const int4*)(aptr);
    pa1 = *(const int4*)(aptr + 4);
    pb0 = *(const float4*)(bptr);
    pb1 = *(const float4*)(bptr + 4);
    pscale = adelta * exp2f(-(float)aeptr[scol >> 5]);
    double acc[8][8];
#pragma unroll
    for (int i = 0; i < 8; ++i)
#pragma unroll
        for (int j = 0; j < 8; ++j) acc[i][j] = 0.0;
    for (int kt = 0; kt < K; kt += TK) {
        {
            float* as = &As[scol][srow];
            as[0*LDT] = (float)pa0.x * pscale; as[1*LDT] = (float)pa0.y * pscale;
            as[2*LDT] = (float)pa0.z * pscale; as[3*LDT] = (float)pa0.w * pscale;
            as[4*LDT] = (float)pa1.x * pscale; as[5*LDT] = (float)pa1.y * pscale;
            as[6*LDT] = (float)pa1.z * pscale; as[7*LDT] = (float)pa1.w * pscale;
            float* bs = &Bs[scol][srow];
            bs[0*LDT] = pb0.x; bs[1*LDT] = pb0.y; bs[2*LDT] = pb0.z; bs[3*LDT] = pb0.w;
            bs[4*LDT] = pb1.x; bs[5*LDT] = pb1.y; bs[6*LDT] = pb1.z; bs[7*LDT] = pb1.w;
        }
        __syncthreads();
        if (kt + TK < K) {
            const int k1 = kt + TK;
            pa0 = *(const int4*)(aptr + k1);
            pa1 = *(const int4*)(aptr + k1 + 4);
            pb0 = *(const float4*)(bptr + k1);
            pb1 = *(const float4*)(bptr + k1 + 4);
            pscale = adelta * exp2f(-(float)aeptr[(k1 + scol) >> 5]);
        }
#pragma unroll
        for (int kk = 0; kk < TK; ++kk) {
            const float4 a0 = *(const float4*)&As[kk][ty * 4];
            const float4 a1 = *(const float4*)&As[kk][64 + ty * 4];
            const float4 b0 = *(const float4*)&Bs[kk][tx * 4];
            const float4 b1 = *(const float4*)&Bs[kk][64 + tx * 4];
            const double ad[8] = {(double)a0.x, (double)a0.y, (double)a0.z, (double)a0.w,
                                  (double)a1.x, (double)a1.y, (double)a1.z, (double)a1.w};
            const double bd[8] = {(double)b0.x, (double)b0.y, (double)b0.z, (double)b0.w,
                                  (double)b1.x, (double)b1.y, (double)b1.z, (double)b1.w};
#pragma unroll
            for (int i = 0; i < 8; ++i)
#pragma unroll
                for (int j = 0; j < 8; ++j)
                    acc[i][j] = fma(ad[i], bd[j], acc[i][j]);
        }
        __syncthreads();
    }
    const float4 bb0 = *(const float4*)&bias[n0 + tx * 4];
    const float4 bb1 = *(const float4*)&bias[n0 + 64 + tx * 4];
#pragma unroll
    for (int i = 0; i < 8; ++i) {
        const int row = m0 + ((i < 4) ? (ty * 4 + i) : (64 + ty * 4 + (i - 4)));
        float4 v0, v1;
        v0.x = (float)(acc[i][0] + (double)bb0.x); v0.y = (float)(acc[i][1] + (double)bb0.y);
        v0.z = (float)(acc[i][2] + (double)bb0.z); v0.w = (float)(acc[i][3] + (double)bb0.w);
        v1.x = (float)(acc[i][4] + (double)bb1.x); v1.y = (float)(acc[i][5] + (double)bb1.y);
        v1.z = (float)(acc[i][6] + (double)bb1.z); v1.w = (float)(acc[i][7] + (double)bb1.w);
        *(float4*)&y[(size_t)row * N + n0 + tx * 4] = v0;
        *(float4*)&y[(size_t)row * N + n0 + 64 + tx * 4] = v1;
    }
}

// ---------------- requant (known-good) ----------------

__global__ __launch_bounds__(256) void requant_kernel(
    float* __restrict__ y, float* __restrict__ odelta,
    float* __restrict__ oe, int N)
{
    const int t = blockIdx.x;
    const int tid = threadIdx.x;
    float* row = y + (size_t)t * N;
    float4 v[4];
    float cmax[4];
    float amax = 0.f;
#pragma unroll
    for (int j = 0; j < 4; ++j) {
        v[j] = *(const float4*)&row[(tid + j * 256) * 4];
        const float m01 = fmaxf(fabsf(v[j].x), fabsf(v[j].y));
        const float m23 = fmaxf(fabsf(v[j].z), fabsf(v[j].w));
        cmax[j] = fmaxf(m01, m23);
        amax = fmaxf(amax, cmax[j]);
    }
    __shared__ float red[256];
    red[tid] = amax;
    __syncthreads();
#pragma unroll
    for (int s = 128; s >= 1; s >>= 1) {
        if (tid < s) red[tid] = fmaxf(red[tid], red[tid + s]);
        __syncthreads();
    }
    const float absmax = red[0];
    const float delta = absmax / 127.0f;
    if (tid == 0) odelta[t] = delta;
    const int G = N >> 5;
#pragma unroll
    for (int j = 0; j < 4; ++j) {
        float gm = cmax[j];
        gm = fmaxf(gm, __shfl_xor(gm, 1));
        gm = fmaxf(gm, __shfl_xor(gm, 2));
        gm = fmaxf(gm, __shfl_xor(gm, 4));
        const float ratio = (delta * 127.0f) / fmaxf(gm, 1e-8f);
        const float rr = fmaxf(ratio, 1.0f);
        float e = floorf(log2f(rr));
        e = fminf(e, 15.0f);
        const float scale = delta * exp2f(-e);
        if ((tid & 7) == 0) oe[(size_t)t * G + (tid >> 3) + 32 * j] = e;
        const float den = fmaxf(scale, 1e-8f);
        float4 q;
        q.x = fminf(fmaxf(rintf(v[j].x / den), -127.f), 127.f);
        q.y = fminf(fmaxf(rintf(v[j].y / den), -127.f), 127.f);
        q.z = fminf(fmaxf(rintf(v[j].z / den), -127.f), 127.f);
        q.w = fminf(fmaxf(rintf(v[j].w / den), -127.f), 127.f);
        *(float4*)&row[(tid + j * 256) * 4] = q;
    }
}

// ---------------- launch ----------------

extern "C" void kernel_launch(void* const* d_in, const int* in_sizes, int n_in,
                              void* d_out, int out_size, void* d_ws, size_t ws_size,
                              hipStream_t stream) {
    const int*   xq     = (const int*)d_in[0];
    const float* xdelta = (const float*)d_in[1];
    const int*   xe     = (const int*)d_in[2];
    const float* W      = (const float*)d_in[3];
    const float* bias   = (const float*)d_in[4];

    const int M = in_sizes[1];            // 8192
    const int K = in_sizes[0] / M;        // 4096
    const int N = in_sizes[4];            // 4096

    float* out    = (float*)d_out;
    float* yq     = out;                  // holds f32 y, then q in-place
    float* odelta = out + (size_t)M * N;
    float* oe     = odelta + M;

    const int Ms = M / 2;                 // stripe rows
    const size_t wplaneSz = (size_t)N * K;
    const size_t xplaneSz = (size_t)Ms * K;
    const size_t need = 4 * wplaneSz + 3 * xplaneSz + 4 * (size_t)(N + M) + 64;

    if ((M % 256) == 0 && (N % 64) == 0 && (K % 64) == 0 && ws_size >= need) {
        char* ws = (char*)d_ws;
        signed char* Wp = (signed char*)ws;                          // 4 planes [K/16][N][16]
        signed char* Xp = (signed char*)(ws + 4 * wplaneSz);         // up to 3 planes
        int*  Ee   = (int*)(ws + 4 * wplaneSz + 3 * xplaneSz);       // [N]
        int*  Cm   = Ee + N;                                         // [M]
        int*  flag = Cm + M;                                         // [1]

        hipMemsetAsync(flag, 0, sizeof(int), stream);
        wprep_rowmax<<<dim3(N), dim3(256), 0, stream>>>(W, Ee, K);
        wprep_planes<<<dim3(K / 64, N / 64), dim3(256), 0, stream>>>(W, Ee, Wp, N, K);
        eguard<<<dim3(M), dim3(128), 0, stream>>>(xe, Cm, flag, K >> 5);
        for (int st = 0; st < 2; ++st) {
            const int mbase = st * Ms;
            xprep2<<<dim3(K / 64, Ms / 64), dim3(256), 0, stream>>>(
                xq, xe, Cm, flag, Xp, mbase, Ms, K);
            gemm_int3<<<dim3(N / 64, Ms / 128), dim3(256), 0, stream>>>(
                Xp, xdelta, Cm, Wp, Ee, bias, flag, yq, Ms, mbase, N, K);
            gemm_int2<<<dim3(N / 64, Ms / 128), dim3(256), 0, stream>>>(
                Xp, xdelta, Wp, Ee, bias, flag, yq, Ms, mbase, N, K);
        }
    } else {
        gemm_dq_kernel<<<dim3(N / TN, M / TM), dim3(256), 0, stream>>>(
            xq, xdelta, xe, W, bias, yq, M, N, K);
    }
    requant_kernel<<<dim3(M), dim3(256), 0, stream>>>(yq, odelta, oe, N);
}